// Round 6
// baseline (373.262 us; speedup 1.0000x reference)
//
#include <hip/hip_runtime.h>

typedef _Float16 f16;
typedef _Float16 f16x4 __attribute__((ext_vector_type(4)));
typedef _Float16 f16x8 __attribute__((ext_vector_type(8)));
typedef float    fx4   __attribute__((ext_vector_type(4)));

#define MODE_PROJ   0
#define MODE_SCORES 1
#define MODE_PV     2

constexpr int Bsz = 4;
constexpr int S   = 2048;
constexpr int DK  = 1024;
constexpr int BM = 128, BN = 128, BK = 64;
constexpr long SD   = (long)S * DK;          // 2M elems
constexpr long SS   = (long)S * S;           // 4M elems
constexpr long BIGN = (long)Bsz * S * DK;    // 8M elems

// async global->LDS, 16B per lane; LDS dest wave-uniform (HW adds lane*16)
__device__ __forceinline__ void glds16(const void* g, void* l) {
    __builtin_amdgcn_global_load_lds(
        (const __attribute__((address_space(1))) void*)g,
        (__attribute__((address_space(3))) void*)l, 16, 0, 0);
}

// Weights fp32 -> f16 (row-major, into ws) + rowsum zeroing. ~18 MB traffic.
__global__ __launch_bounds__(256)
void wconvert_kernel(const float* wq, const float* wk, const float* wv,
                     f16* wqh, f16* wkh, f16* wvh, float* rowsum)
{
    int bx = blockIdx.x;
    if (bx < 1536) {                      // 512 blocks x 2048 elems per weight
        int t = bx >> 9, blk = bx & 511;
        const float* src = (t == 0) ? wq : (t == 1) ? wk : wv;
        f16*         dst = (t == 0) ? wqh : (t == 1) ? wkh : wvh;
        size_t off = (size_t)blk * 2048 + (size_t)threadIdx.x * 8;
        float4 f0 = *(const float4*)(src + off);
        float4 f1 = *(const float4*)(src + off + 4);
        f16x8 h = {(f16)f0.x, (f16)f0.y, (f16)f0.z, (f16)f0.w,
                   (f16)f1.x, (f16)f1.y, (f16)f1.z, (f16)f1.w};
        *(f16x8*)(dst + off) = h;
    } else {                              // 4 blocks zero rowsum (8192 floats)
        int blk = bx - 1536;
        size_t off = (size_t)blk * 2048 + (size_t)threadIdx.x * 8;
        fx4 z4 = {0.f, 0.f, 0.f, 0.f};
        *(fx4*)(rowsum + off)     = z4;
        *(fx4*)(rowsum + off + 4) = z4;
    }
}

// NT GEMM, 128x128x64 tiles, 4 waves (2x2), 4x4 16x16x32 MFMA per wave.
// All staging via async glds16. XCD swizzle on block ids.
// MODE_PROJ: A staged as fp32 (32 KB LDS), converted f32->f16 at fragment read;
//            B = f16 weights (16 KB LDS).  Others: both f16 (32 KB total).
template<int MODE>
__global__ __launch_bounds__(256, MODE == MODE_PROJ ? 3 : 4)
void gemm_kernel(const float* Fq, const float* Fk, const float* Fv,
                 const f16* B0, const f16* B1, const f16* B2,
                 const f16* A0,
                 void* O0, void* O1, float* rowsum,
                 int lda, int ldb, int K, int ldo)
{
    __shared__ __align__(16) char smem[MODE == MODE_PROJ ? 49152 : 32768];
    float* lAf = (float*)smem;                 // PROJ: 32 KB fp32 A
    f16*   lAh = (f16*)smem;                   // others: 16 KB f16 A
    f16*   lB  = (f16*)(smem + (MODE == MODE_PROJ ? 32768 : 16384));

    const int tid = threadIdx.x;
    const int id  = blockIdx.x;
    const int z   = blockIdx.y;
    int row0, col0;
    if constexpr (MODE == MODE_PROJ) { row0 = (id & 63) * BM; col0 = (id >> 6) * BN; }
    else                             { row0 = (id & 15) * BM; col0 = (id >> 4) * BN; }

    const int lane = tid & 63;
    const int quad = lane >> 4;
    const int cn   = lane & 15;
    const int w    = tid >> 6;
    const int wm   = w >> 1;
    const int wn   = w & 1;

    const float* Afp = nullptr;
    const f16 *Ap = nullptr, *Bp;
    if constexpr (MODE == MODE_PROJ) {
        Afp = (z == 0) ? Fq : (z == 1) ? Fk : Fv;
        Bp  = (z == 0) ? B0 : (z == 1) ? B1 : B2;
    } else if constexpr (MODE == MODE_SCORES) {
        Ap = A0 + (long)z * SD;  Bp = B0 + (long)z * SD;
        rowsum += (long)z * S;
    } else {
        Ap = A0 + (long)z * SS;  Bp = B0 + (long)z * SD;
        rowsum += (long)z * S;
    }

    fx4 acc[4][4];
    #pragma unroll
    for (int mt = 0; mt < 4; ++mt)
        #pragma unroll
        for (int nt = 0; nt < 4; ++nt)
            acc[mt][nt] = (fx4){0.f, 0.f, 0.f, 0.f};

    // f16 staging lane map (B always; A in non-proj): 8 rows x 8 chunks of 16B,
    // fetch XOR-permuted so physical chunk p of row r holds global chunk p^(r&7)
    const int lr8 = lane >> 3;
    const int lcS = ((lane & 7) ^ lr8) << 3;
    // fp32 A staging lane map (proj): 4 rows x 16 chunks of 16B (4 floats);
    // even-only XOR keeps b128 adjacency: global chunk = p ^ (2*(r&7))
    const int lr4 = lane >> 4;            // 0..3 row in group
    const int ch16 = lane & 15;           // physical chunk

    for (int k0 = 0; k0 < K; k0 += BK) {
        __syncthreads();
        if constexpr (MODE == MODE_PROJ) {
            #pragma unroll
            for (int i = 0; i < 4; ++i) {   // B: f16 weights
                int rb = w * 32 + i * 8;
                glds16(Bp + (size_t)(col0 + rb + lr8) * ldb + k0 + lcS, &lB[rb * BK]);
            }
            #pragma unroll
            for (int i = 0; i < 8; ++i) {   // A: fp32, async
                int rb = w * 32 + i * 4;    // wave-uniform
                int r  = rb + lr4;
                int gc = ch16 ^ (2 * (r & 7));
                glds16(Afp + (size_t)(row0 + r) * lda + k0 + gc * 4, &lAf[rb * BK]);
            }
        } else {
            #pragma unroll
            for (int i = 0; i < 4; ++i) {
                int rb = w * 32 + i * 8;
                glds16(Ap + (size_t)(row0 + rb + lr8) * lda + k0 + lcS, &lAh[rb * BK]);
                glds16(Bp + (size_t)(col0 + rb + lr8) * ldb + k0 + lcS, &lB[rb * BK]);
            }
        }
        __syncthreads();

        #pragma unroll
        for (int kh = 0; kh < 2; ++kh) {
            f16x8 af[4], bf[4];
            #pragma unroll
            for (int mt = 0; mt < 4; ++mt) {
                int r = wm * 64 + mt * 16 + cn;
                if constexpr (MODE == MODE_PROJ) {
                    int pc = (kh * 8 + quad * 2) ^ (2 * (r & 7));  // even-chunk XOR
                    const float* p = &lAf[r * BK + pc * 4];
                    float4 lo = *(const float4*)p;
                    float4 hi = *(const float4*)(p + 4);
                    af[mt] = (f16x8){(f16)lo.x, (f16)lo.y, (f16)lo.z, (f16)lo.w,
                                     (f16)hi.x, (f16)hi.y, (f16)hi.z, (f16)hi.w};
                } else {
                    int ch = ((kh << 2) | quad) ^ (r & 7);
                    af[mt] = *(const f16x8*)&lAh[r * BK + ch * 8];
                }
            }
            #pragma unroll
            for (int nt = 0; nt < 4; ++nt) {
                int r = wn * 64 + nt * 16 + cn;
                int ch = ((kh << 2) | quad) ^ (r & 7);
                bf[nt] = *(const f16x8*)&lB[r * BK + ch * 8];
            }
            #pragma unroll
            for (int mt = 0; mt < 4; ++mt)
                #pragma unroll
                for (int nt = 0; nt < 4; ++nt)
                    acc[mt][nt] = __builtin_amdgcn_mfma_f32_16x16x32_f16(
                        af[mt], bf[nt], acc[mt][nt], 0, 0, 0);
        }
    }

    // C/D layout: col = lane&15, row = quad*4 + reg
    if constexpr (MODE == MODE_PROJ) {
        if (z < 2) {
            f16* O = (f16*)O0 + (long)z * BIGN;   // qp / kp
            #pragma unroll
            for (int mt = 0; mt < 4; ++mt) {
                int r0 = row0 + wm * 64 + mt * 16 + quad * 4;
                #pragma unroll
                for (int nt = 0; nt < 4; ++nt) {
                    int c = col0 + wn * 64 + nt * 16 + cn;
                    #pragma unroll
                    for (int reg = 0; reg < 4; ++reg)
                        O[(size_t)(r0 + reg) * DK + c] = (f16)acc[mt][nt][reg];
                }
            }
        } else {
            // v: transposed store -> vpT[b][e][s]
            #pragma unroll
            for (int mt = 0; mt < 4; ++mt) {
                int r0 = row0 + wm * 64 + mt * 16 + quad * 4;
                int b  = r0 >> 11;
                int s  = r0 & 2047;
                f16* O = (f16*)O1 + (long)b * SD;
                #pragma unroll
                for (int nt = 0; nt < 4; ++nt) {
                    int c = col0 + wn * 64 + nt * 16 + cn;
                    f16x4 h = {(f16)acc[mt][nt][0], (f16)acc[mt][nt][1],
                               (f16)acc[mt][nt][2], (f16)acc[mt][nt][3]};
                    *(f16x4*)&O[(size_t)c * S + s] = h;
                }
            }
        }
    } else if constexpr (MODE == MODE_SCORES) {
        f16* O = (f16*)O0 + (long)z * SS;
        const float sl2e = 0.03125f * 1.44269504f;  // (1/32)*log2(e)
        float rs[4][4];
        #pragma unroll
        for (int mt = 0; mt < 4; ++mt)
            #pragma unroll
            for (int reg = 0; reg < 4; ++reg) rs[mt][reg] = 0.f;
        #pragma unroll
        for (int mt = 0; mt < 4; ++mt) {
            int r0 = row0 + wm * 64 + mt * 16 + quad * 4;
            #pragma unroll
            for (int nt = 0; nt < 4; ++nt) {
                int c = col0 + wn * 64 + nt * 16 + cn;
                #pragma unroll
                for (int reg = 0; reg < 4; ++reg) {
                    float vv = exp2f(acc[mt][nt][reg] * sl2e);
                    rs[mt][reg] += vv;
                    O[(size_t)(r0 + reg) * ldo + c] = (f16)vv;
                }
            }
        }
        #pragma unroll
        for (int mt = 0; mt < 4; ++mt) {
            int r0 = row0 + wm * 64 + mt * 16 + quad * 4;
            #pragma unroll
            for (int reg = 0; reg < 4; ++reg) {
                float vv = rs[mt][reg];
                vv += __shfl_xor(vv, 1);
                vv += __shfl_xor(vv, 2);
                vv += __shfl_xor(vv, 4);
                vv += __shfl_xor(vv, 8);
                if (cn == 0) atomicAdd(&rowsum[r0 + reg], vv);
            }
        }
    } else {  // MODE_PV
        float* O = (float*)O0 + (long)z * SD;
        #pragma unroll
        for (int mt = 0; mt < 4; ++mt) {
            int r0 = row0 + wm * 64 + mt * 16 + quad * 4;
            fx4 rsv = *(const fx4*)&rowsum[r0];
            fx4 inv = {1.f / rsv[0], 1.f / rsv[1], 1.f / rsv[2], 1.f / rsv[3]};
            #pragma unroll
            for (int nt = 0; nt < 4; ++nt) {
                int c = col0 + wn * 64 + nt * 16 + cn;
                #pragma unroll
                for (int reg = 0; reg < 4; ++reg)
                    O[(size_t)(r0 + reg) * ldo + c] = acc[mt][nt][reg] * inv[reg];
            }
        }
    }
}

extern "C" void kernel_launch(void* const* d_in, const int* in_sizes, int n_in,
                              void* d_out, int out_size, void* d_ws, size_t ws_size,
                              hipStream_t stream) {
    const float* q  = (const float*)d_in[0];
    const float* k  = (const float*)d_in[1];
    const float* v  = (const float*)d_in[2];
    const float* wq = (const float*)d_in[3];
    const float* wk = (const float*)d_in[4];
    const float* wv = (const float*)d_in[5];
    float* out = (float*)d_out;

    char* ws = (char*)d_ws;
    f16*   qp     = (f16*)(ws);                          // 16 MB [8192, 1024]
    f16*   kp     = (f16*)(ws + ((size_t)16 << 20));     // 16 MB [8192, 1024]
    f16*   vpT    = (f16*)(ws + ((size_t)32 << 20));     // 16 MB [B][DK][S]
    f16*   E      = (f16*)(ws + ((size_t)48 << 20));     // 32 MB [B][S][S]
    float* rowsum = (float*)(ws + ((size_t)80 << 20));   // 32 KB [B][S]
    f16*   wqh    = (f16*)(ws + ((size_t)81 << 20));     // 2 MB each
    f16*   wkh    = (f16*)(ws + ((size_t)83 << 20));
    f16*   wvh    = (f16*)(ws + ((size_t)85 << 20));

    // weights fp32->f16 + rowsum zeroing (one small dispatch)
    wconvert_kernel<<<1540, 256, 0, stream>>>(wq, wk, wv, wqh, wkh, wvh, rowsum);

    dim3 blk(256);
    // fused projections: y=0 -> qp, y=1 -> kp, y=2 -> vpT (transposed);
    // A read as fp32 via async glds16, converted at fragment-read.
    gemm_kernel<MODE_PROJ><<<dim3(512, 3), blk, 0, stream>>>(
        q, k, v, wqh, wkh, wvh, nullptr, qp, vpT, nullptr, DK, DK, DK, DK);
    // scores: E = exp(qp.kp/32), rowsum accumulated
    gemm_kernel<MODE_SCORES><<<dim3(256, 4), blk, 0, stream>>>(
        nullptr, nullptr, nullptr, kp, nullptr, nullptr, qp, E, nullptr, rowsum,
        DK, DK, DK, S);
    // PV: out = (E @ vpT^T) / rowsum
    gemm_kernel<MODE_PV><<<dim3(128, 4), blk, 0, stream>>>(
        nullptr, nullptr, nullptr, vpT, nullptr, nullptr, E, out, nullptr, rowsum,
        S, S, S, DK);
}

// Round 7
// 302.246 us; speedup vs baseline: 1.2350x; 1.2350x over previous
//
#include <hip/hip_runtime.h>

typedef _Float16 f16;
typedef _Float16 f16x4 __attribute__((ext_vector_type(4)));
typedef _Float16 f16x8 __attribute__((ext_vector_type(8)));
typedef float    fx4   __attribute__((ext_vector_type(4)));

#define MODE_PROJ   0
#define MODE_SCORES 1
#define MODE_PV     2

constexpr int Bsz = 4;
constexpr int S   = 2048;
constexpr int DK  = 1024;
constexpr int BM = 128, BN = 128, BK = 64;
constexpr long SD   = (long)S * DK;          // 2M elems
constexpr long SS   = (long)S * S;           // 4M elems
constexpr long BIGN = (long)Bsz * S * DK;    // 8M elems

// async global->LDS, 16B per lane; LDS dest wave-uniform (HW adds lane*16)
__device__ __forceinline__ void glds16(const void* g, void* l) {
    __builtin_amdgcn_global_load_lds(
        (const __attribute__((address_space(1))) void*)g,
        (__attribute__((address_space(3))) void*)l, 16, 0, 0);
}

// Weights fp32 -> f16 (row-major, into ws) + rowsum zeroing. ~18 MB traffic.
__global__ __launch_bounds__(256)
void wconvert_kernel(const float* wq, const float* wk, const float* wv,
                     f16* wqh, f16* wkh, f16* wvh, float* rowsum)
{
    int bx = blockIdx.x;
    if (bx < 1536) {                      // 512 blocks x 2048 elems per weight
        int t = bx >> 9, blk = bx & 511;
        const float* src = (t == 0) ? wq : (t == 1) ? wk : wv;
        f16*         dst = (t == 0) ? wqh : (t == 1) ? wkh : wvh;
        size_t off = (size_t)blk * 2048 + (size_t)threadIdx.x * 8;
        float4 f0 = *(const float4*)(src + off);
        float4 f1 = *(const float4*)(src + off + 4);
        f16x8 h = {(f16)f0.x, (f16)f0.y, (f16)f0.z, (f16)f0.w,
                   (f16)f1.x, (f16)f1.y, (f16)f1.z, (f16)f1.w};
        *(f16x8*)(dst + off) = h;
    } else {                              // 4 blocks zero rowsum (8192 floats)
        int blk = bx - 1536;
        size_t off = (size_t)blk * 2048 + (size_t)threadIdx.x * 8;
        fx4 z4 = {0.f, 0.f, 0.f, 0.f};
        *(fx4*)(rowsum + off)     = z4;
        *(fx4*)(rowsum + off + 4) = z4;
    }
}

// NT GEMM, 128x128x64 tiles, 4 waves (2x2), 4x4 16x16x32 MFMA per wave.
// All staging async glds16; XCD swizzle on block ids; XOR bank swizzle in LDS.
// MODE_PROJ: A fp32 (32 KB LDS), cvt f32->f16 at fragment read; B f16 weights.
//   A swizzle: phys chunk p (16B) of row r holds global chunk p^(r&7); fragment
//   chunks L0=kh*8+quad*2, L0+1 read at phys L^(r&7) -> bank groups (2q^c)%8 and
//   ((2q+1)^c)%8: 8 lanes/group over all 8 groups = R4's measured-zero geometry.
// MODE_SCORES/PV: both f16, chunk^(r&7) swizzle (R4-proven, 0 conflicts).
template<int MODE>
__global__ __launch_bounds__(256, MODE == MODE_PROJ ? 3 : 4)
void gemm_kernel(const float* Fq, const float* Fk, const float* Fv,
                 const f16* B0, const f16* B1, const f16* B2,
                 const f16* A0,
                 void* O0, void* O1, float* rowsum,
                 int lda, int ldb, int K, int ldo)
{
    __shared__ __align__(16) char smem[MODE == MODE_PROJ ? 49152 : 32768];
    float* lAf = (float*)smem;                 // PROJ: 32 KB fp32 A (row stride 64)
    f16*   lAh = (f16*)smem;                   // others: 16 KB f16 A
    f16*   lB  = (f16*)(smem + (MODE == MODE_PROJ ? 32768 : 16384));

    const int tid = threadIdx.x;
    const int id  = blockIdx.x;
    const int z   = blockIdx.y;
    int row0, col0;
    if constexpr (MODE == MODE_PROJ) { row0 = (id & 63) * BM; col0 = (id >> 6) * BN; }
    else                             { row0 = (id & 15) * BM; col0 = (id >> 4) * BN; }

    const int lane = tid & 63;
    const int quad = lane >> 4;
    const int cn   = lane & 15;
    const int w    = tid >> 6;
    const int wm   = w >> 1;
    const int wn   = w & 1;

    const float* Afp = nullptr;
    const f16 *Ap = nullptr, *Bp;
    if constexpr (MODE == MODE_PROJ) {
        Afp = (z == 0) ? Fq : (z == 1) ? Fk : Fv;
        Bp  = (z == 0) ? B0 : (z == 1) ? B1 : B2;
    } else if constexpr (MODE == MODE_SCORES) {
        Ap = A0 + (long)z * SD;  Bp = B0 + (long)z * SD;
        rowsum += (long)z * S;
    } else {
        Ap = A0 + (long)z * SS;  Bp = B0 + (long)z * SD;
        rowsum += (long)z * S;
    }

    fx4 acc[4][4];
    #pragma unroll
    for (int mt = 0; mt < 4; ++mt)
        #pragma unroll
        for (int nt = 0; nt < 4; ++nt)
            acc[mt][nt] = (fx4){0.f, 0.f, 0.f, 0.f};

    // f16 staging lane map: 8 rows x 8 chunks of 16B, phys chunk p holds p^(r&7)
    const int lr8 = lane >> 3;
    const int lcS = ((lane & 7) ^ lr8) << 3;
    // fp32 A staging lane map: 4 rows x 16 chunks of 16B
    const int lr4  = lane >> 4;           // row within 4-row group
    const int ch16 = lane & 15;           // physical chunk

    for (int k0 = 0; k0 < K; k0 += BK) {
        __syncthreads();
        if constexpr (MODE == MODE_PROJ) {
            #pragma unroll
            for (int i = 0; i < 4; ++i) {   // B: f16 weights
                int rb = w * 32 + i * 8;
                glds16(Bp + (size_t)(col0 + rb + lr8) * ldb + k0 + lcS, &lB[rb * BK]);
            }
            #pragma unroll
            for (int i = 0; i < 8; ++i) {   // A: fp32, async, chunk^(r&7)
                int rb = w * 32 + i * 4;    // wave-uniform
                int s  = (i * 4 + lr4) & 7; // == (rb+lr4)&7  (w*32 ≡ 0 mod 8)
                int g  = ch16 ^ s;
                glds16(Afp + (size_t)(row0 + rb + lr4) * lda + k0 + g * 4,
                       &lAf[rb * BK]);
            }
        } else {
            #pragma unroll
            for (int i = 0; i < 4; ++i) {
                int rb = w * 32 + i * 8;
                glds16(Ap + (size_t)(row0 + rb + lr8) * lda + k0 + lcS, &lAh[rb * BK]);
                glds16(Bp + (size_t)(col0 + rb + lr8) * ldb + k0 + lcS, &lB[rb * BK]);
            }
        }
        __syncthreads();

        #pragma unroll
        for (int kh = 0; kh < 2; ++kh) {
            f16x8 af[4], bf[4];
            #pragma unroll
            for (int mt = 0; mt < 4; ++mt) {
                int r = wm * 64 + mt * 16 + cn;
                if constexpr (MODE == MODE_PROJ) {
                    int s7 = r & 7;
                    int L0 = kh * 8 + quad * 2;
                    float4 lo = *(const float4*)&lAf[r * BK + ((L0 ^ s7) << 2)];
                    float4 hi = *(const float4*)&lAf[r * BK + (((L0 + 1) ^ s7) << 2)];
                    af[mt] = (f16x8){(f16)lo.x, (f16)lo.y, (f16)lo.z, (f16)lo.w,
                                     (f16)hi.x, (f16)hi.y, (f16)hi.z, (f16)hi.w};
                } else {
                    int ch = ((kh << 2) | quad) ^ (r & 7);
                    af[mt] = *(const f16x8*)&lAh[r * BK + ch * 8];
                }
            }
            #pragma unroll
            for (int nt = 0; nt < 4; ++nt) {
                int r = wn * 64 + nt * 16 + cn;
                int ch = ((kh << 2) | quad) ^ (r & 7);
                bf[nt] = *(const f16x8*)&lB[r * BK + ch * 8];
            }
            #pragma unroll
            for (int mt = 0; mt < 4; ++mt)
                #pragma unroll
                for (int nt = 0; nt < 4; ++nt)
                    acc[mt][nt] = __builtin_amdgcn_mfma_f32_16x16x32_f16(
                        af[mt], bf[nt], acc[mt][nt], 0, 0, 0);
        }
    }

    // C/D layout: col = lane&15, row = quad*4 + reg
    if constexpr (MODE == MODE_PROJ) {
        if (z < 2) {
            f16* O = (f16*)O0 + (long)z * BIGN;   // qp / kp
            #pragma unroll
            for (int mt = 0; mt < 4; ++mt) {
                int r0 = row0 + wm * 64 + mt * 16 + quad * 4;
                #pragma unroll
                for (int nt = 0; nt < 4; ++nt) {
                    int c = col0 + wn * 64 + nt * 16 + cn;
                    #pragma unroll
                    for (int reg = 0; reg < 4; ++reg)
                        O[(size_t)(r0 + reg) * DK + c] = (f16)acc[mt][nt][reg];
                }
            }
        } else {
            // v: transposed store -> vpT[b][e][s]
            #pragma unroll
            for (int mt = 0; mt < 4; ++mt) {
                int r0 = row0 + wm * 64 + mt * 16 + quad * 4;
                int b  = r0 >> 11;
                int s  = r0 & 2047;
                f16* O = (f16*)O1 + (long)b * SD;
                #pragma unroll
                for (int nt = 0; nt < 4; ++nt) {
                    int c = col0 + wn * 64 + nt * 16 + cn;
                    f16x4 h = {(f16)acc[mt][nt][0], (f16)acc[mt][nt][1],
                               (f16)acc[mt][nt][2], (f16)acc[mt][nt][3]};
                    *(f16x4*)&O[(size_t)c * S + s] = h;
                }
            }
        }
    } else if constexpr (MODE == MODE_SCORES) {
        f16* O = (f16*)O0 + (long)z * SS;
        const float sl2e = 0.03125f * 1.44269504f;  // (1/32)*log2(e)
        float rs[4][4];
        #pragma unroll
        for (int mt = 0; mt < 4; ++mt)
            #pragma unroll
            for (int reg = 0; reg < 4; ++reg) rs[mt][reg] = 0.f;
        #pragma unroll
        for (int mt = 0; mt < 4; ++mt) {
            int r0 = row0 + wm * 64 + mt * 16 + quad * 4;
            #pragma unroll
            for (int nt = 0; nt < 4; ++nt) {
                int c = col0 + wn * 64 + nt * 16 + cn;
                #pragma unroll
                for (int reg = 0; reg < 4; ++reg) {
                    float vv = exp2f(acc[mt][nt][reg] * sl2e);
                    rs[mt][reg] += vv;
                    O[(size_t)(r0 + reg) * ldo + c] = (f16)vv;
                }
            }
        }
        #pragma unroll
        for (int mt = 0; mt < 4; ++mt) {
            int r0 = row0 + wm * 64 + mt * 16 + quad * 4;
            #pragma unroll
            for (int reg = 0; reg < 4; ++reg) {
                float vv = rs[mt][reg];
                vv += __shfl_xor(vv, 1);
                vv += __shfl_xor(vv, 2);
                vv += __shfl_xor(vv, 4);
                vv += __shfl_xor(vv, 8);
                if (cn == 0) atomicAdd(&rowsum[r0 + reg], vv);
            }
        }
    } else {  // MODE_PV
        float* O = (float*)O0 + (long)z * SD;
        #pragma unroll
        for (int mt = 0; mt < 4; ++mt) {
            int r0 = row0 + wm * 64 + mt * 16 + quad * 4;
            fx4 rsv = *(const fx4*)&rowsum[r0];
            fx4 inv = {1.f / rsv[0], 1.f / rsv[1], 1.f / rsv[2], 1.f / rsv[3]};
            #pragma unroll
            for (int nt = 0; nt < 4; ++nt) {
                int c = col0 + wn * 64 + nt * 16 + cn;
                #pragma unroll
                for (int reg = 0; reg < 4; ++reg)
                    O[(size_t)(r0 + reg) * ldo + c] = acc[mt][nt][reg] * inv[reg];
            }
        }
    }
}

extern "C" void kernel_launch(void* const* d_in, const int* in_sizes, int n_in,
                              void* d_out, int out_size, void* d_ws, size_t ws_size,
                              hipStream_t stream) {
    const float* q  = (const float*)d_in[0];
    const float* k  = (const float*)d_in[1];
    const float* v  = (const float*)d_in[2];
    const float* wq = (const float*)d_in[3];
    const float* wk = (const float*)d_in[4];
    const float* wv = (const float*)d_in[5];
    float* out = (float*)d_out;

    char* ws = (char*)d_ws;
    f16*   qp     = (f16*)(ws);                          // 16 MB [8192, 1024]
    f16*   kp     = (f16*)(ws + ((size_t)16 << 20));     // 16 MB [8192, 1024]
    f16*   vpT    = (f16*)(ws + ((size_t)32 << 20));     // 16 MB [B][DK][S]
    f16*   E      = (f16*)(ws + ((size_t)48 << 20));     // 32 MB [B][S][S]
    float* rowsum = (float*)(ws + ((size_t)80 << 20));   // 32 KB [B][S]
    f16*   wqh    = (f16*)(ws + ((size_t)81 << 20));     // 2 MB each
    f16*   wkh    = (f16*)(ws + ((size_t)83 << 20));
    f16*   wvh    = (f16*)(ws + ((size_t)85 << 20));

    // weights fp32->f16 + rowsum zeroing (one small dispatch)
    wconvert_kernel<<<1540, 256, 0, stream>>>(wq, wk, wv, wqh, wkh, wvh, rowsum);

    dim3 blk(256);
    // fused projections: y=0 -> qp, y=1 -> kp, y=2 -> vpT (transposed);
    // A read as fp32 via async glds16, cvt at fragment read.
    gemm_kernel<MODE_PROJ><<<dim3(512, 3), blk, 0, stream>>>(
        q, k, v, wqh, wkh, wvh, nullptr, qp, vpT, nullptr, DK, DK, DK, DK);
    // scores: E = exp(qp.kp/32), rowsum accumulated
    gemm_kernel<MODE_SCORES><<<dim3(256, 4), blk, 0, stream>>>(
        nullptr, nullptr, nullptr, kp, nullptr, nullptr, qp, E, nullptr, rowsum,
        DK, DK, DK, S);
    // PV: out = (E @ vpT^T) / rowsum
    gemm_kernel<MODE_PV><<<dim3(128, 4), blk, 0, stream>>>(
        nullptr, nullptr, nullptr, vpT, nullptr, nullptr, E, out, nullptr, rowsum,
        S, S, S, DK);
}